// Round 24
// baseline (46.756 us; speedup 1.0000x reference)
//
#include <hip/hip_runtime.h>
#include <hip/hip_bf16.h>

// ShuffleNet fused block-MLP, MI355X (gfx950).  R24 = R23 + epilogue-VALU cuts:
//  (a) bias folded into MFMA accumulator INIT (b1 frags stored f32; acc = bias,
//      not 0) — removes 256 adds + 128 bf16 unpacks per wave;
//  (b) v_cvt_pk_bf16_f32 (1 instr per 2 elems, HW RNE) replaces the ~9-instr
//      __float2bfloat16 pair path in fused + pack_x.
// R22 counters attributed fused's 35us to ~1800 epilogue VALU/wave at 34%
// utilization; these cuts take it to ~750.
// Math = R11..R23 (passed, absmax 9.77e-4): pi-permuted w2 pack makes GEMM2's
// A-frag the lane's own GEMM1 outputs; pi(k)=32*(k>>5)+16*((k>>2)&1)+4*((k>>3)&3)+(k&3).
// xT frag (rt,n,ks): lane l elem e = bf16(x[rt*16+(l&15)][n*64+ks*32+(l>>4)*8+e])
//   at xT[rt*16384 + (n*2+ks)*512 + l*8 + e]  (per-rt contiguous 32KB).

typedef __attribute__((ext_vector_type(8))) short  short8;
typedef __attribute__((ext_vector_type(4))) short  short4v;
typedef __attribute__((ext_vector_type(4))) float  floatx4;
typedef __attribute__((ext_vector_type(2))) int    int2v;

#define XP 1032

__device__ __forceinline__ short f2bf(float f) {
  union { __hip_bfloat16 h; short s; } u;
  u.h = __float2bfloat16(f);
  return u.s;
}
// packed f32x2 -> bf16x2, one VALU instr (gfx950; RNE per HW mode)
__device__ __forceinline__ int cvtpk(float a, float b) {
  int r;
  asm("v_cvt_pk_bf16_f32 %0, %1, %2" : "=v"(r) : "v"(a), "v"(b));
  return r;
}

// gelu(v) ~= v * sigmoid(1.5957691*(v + 0.044715 v^3)), exp2-folded (abs<5e-4)
__device__ __forceinline__ float gelu_f(float v) {
  float m = v * v;
  float c = fmaf(-0.1029375f, m, -2.3020807f);
  float z = v * c;
  float e = __builtin_amdgcn_exp2f(z);
  return v * __builtin_amdgcn_rcpf(1.0f + e);
}

// ---- pack kernel: w1 frags | w2 frags (pi-permuted) | b1 frags (f32) ----
__global__ void pack_k(const float* __restrict__ w1, const float* __restrict__ w2,
                       const float* __restrict__ b1, short* __restrict__ w1p,
                       short* __restrict__ w2p, float* __restrict__ b1pf) {
  const int t = blockIdx.x * blockDim.x + threadIdx.x;  // 160*512 = 81920
  const int lane = t & 63;
  const int lhi = lane >> 4;
  if (t < 32768) {  // w1 frag (n,np,ks)
    const int ks = (t >> 6) & 1, np = (t >> 7) & 15, n = (t >> 11) & 15;
    const float* src = w1 + ((size_t)(n * 256 + np * 16 + (lane & 15)) * 64 + ks * 32 + lhi * 8);
    short8 f;
#pragma unroll
    for (int e = 0; e < 8; ++e) f[e] = f2bf(src[e]);
    *(short8*)(w1p + (size_t)t * 8) = f;
  } else if (t < 65536) {  // w2 frag (np,s,ot), pi-permuted k
    const int t2 = t - 32768;
    const int ot = (t2 >> 6) & 3, s = (t2 >> 8) & 7, np = (t2 >> 11) & 15;
    const int op = ot * 16 + (lane & 15);
    short8 f;
#pragma unroll
    for (int e = 0; e < 8; ++e) {
      const int Kc = 32 * s + 16 * ((e >> 2) & 1) + 4 * lhi + (e & 3);
      const int n = Kc >> 4, ohi = Kc & 15;
      f[e] = f2bf(w2[(size_t)(np * 64 + op) * 256 + ohi * 16 + n]);
    }
    *(short8*)(w2p + (size_t)t2 * 8) = f;
  } else {  // b1 frag (n,np), f32: lane l reg r = b1[(np*16+lhi*4+r)*16+n]
    const int t3 = t - 65536;  // 16384
    const int np = (t3 >> 6) & 15, n = (t3 >> 10) & 15;
    floatx4 b;
#pragma unroll
    for (int r = 0; r < 4; ++r) b[r] = b1[(np * 16 + lhi * 4 + r) * 16 + n];
    *(floatx4*)(b1pf + ((size_t)(n * 16 + np) * 64 + lane) * 4) = b;
  }
}

// ---- pack_x: LDS-staged transpose; block g -> rt g (XCD g&7). 512 x 256. ----
__global__ __launch_bounds__(256, 4) void pack_x(
    const float* __restrict__ x, short* __restrict__ xT) {
  __shared__ __align__(16) short xs[16 * XP];
  const int tid = threadIdx.x;
  const int wv = tid >> 6, lane = tid & 63;
  const int l15 = lane & 15, lhi = lane >> 4;
  const int rt = blockIdx.x;

#pragma unroll
  for (int j = 0; j < 16; ++j) {
    floatx4 v = __builtin_nontemporal_load(
        (const floatx4*)(x + (size_t)(rt * 16 + j) * 1024 + tid * 4));
    int2v p;
    p[0] = cvtpk(v[0], v[1]);
    p[1] = cvtpk(v[2], v[3]);
    *(int2v*)(&xs[j * XP + tid * 4]) = p;
  }
  __syncthreads();

#pragma unroll
  for (int i = 0; i < 8; ++i) {
    const int f = wv * 8 + i, n = f >> 1, ks = f & 1;
    short8 fr = *(const short8*)(&xs[l15 * XP + n * 64 + ks * 32 + lhi * 8]);
    *(short8*)(xT + (size_t)rt * 16384 + (n * 2 + ks) * 512 + lane * 8) = fr;
  }
}

// ---- fused: 1024 WGs x 512 thr; np = b>>6, g = b&63; wave wv: rt = wv*64+g ----
__global__ __launch_bounds__(512, 6) void fused_k(
    const short* __restrict__ xT, const short* __restrict__ w1p,
    const short* __restrict__ w2p, const float* __restrict__ b1pf,
    const float* __restrict__ b2, float* __restrict__ y) {
  __shared__ __align__(16) short lw1[16384];  // 32 KB: w1 np-slice (frag order)
  __shared__ __align__(16) float lb1f[4096];  // 16 KB: b1 np-slice (f32 frags)

  const int tid = threadIdx.x;
  const int wv = tid >> 6, lane = tid & 63;
  const int l15 = lane & 15, lhi = lane >> 4;
  const int np = blockIdx.x >> 6;              // 0..15
  const int g  = blockIdx.x & 63;              // XCD = g&7
  const int rt = wv * 64 + g;                  // rt = g (mod 8): pack_x writer XCD

  // ---- stage w1 (bf16 frags) + b1 (f32 frags): 48 KB ----
#pragma unroll
  for (int i = 0; i < 4; ++i) {                // lw1: 2048 short8, chunk c = n*2+ks
    const int u = i * 512 + tid;
    const int c = u >> 6, e = u & 63;
    const size_t so = (((size_t)(c >> 1) * 16 + np) * 2 + (c & 1)) * 512 + e * 8;
    *(short8*)(&lw1[c * 512 + e * 8]) = *(const short8*)(w1p + so);
  }
#pragma unroll
  for (int i = 0; i < 2; ++i) {                // lb1f: 1024 float4
    const int u = i * 512 + tid;
    const int n_ = u >> 6, e_ = u & 63;
    *(floatx4*)(&lb1f[n_ * 256 + e_ * 4]) =
        *(const floatx4*)(b1pf + ((size_t)(n_ * 16 + np) * 64 + e_) * 4);
  }
  __syncthreads();   // the only barrier

  // ---- hoisted base pointers; per-step offsets are constants ----
  const short* px = xT + (size_t)rt * 16384 + lane * 8;
  const short* pw = w2p + (size_t)np * 16384 + lane * 8;
  const short* lw = lw1 + lane * 8;
  const float* lbf = lb1f + lane * 4;          // frag for n at +n*256

  floatx4 c0 = {0.f,0.f,0.f,0.f}, c1 = {0.f,0.f,0.f,0.f};
  floatx4 c2 = {0.f,0.f,0.f,0.f}, c3 = {0.f,0.f,0.f,0.f};

  short8 xA0, xA1, xA2, xA3, xB0, xB1, xB2, xB3;
#define XLOAD(P0, P1, P2, P3, ss) {                      \
  P0 = *(const short8*)(px + (ss) * 2048 + 0);           \
  P1 = *(const short8*)(px + (ss) * 2048 + 512);         \
  P2 = *(const short8*)(px + (ss) * 2048 + 1024);        \
  P3 = *(const short8*)(px + (ss) * 2048 + 1536);        \
}
  XLOAD(xA0, xA1, xA2, xA3, 0)

#pragma unroll
  for (int s = 0; s < 8; ++s) {
    // w2 B-frags for this step (global L2; hidden under GEMM1+gelu)
    short8 bf0  = *(const short8*)(pw + s * 2048 + 0);
    short8 bf1  = *(const short8*)(pw + s * 2048 + 512);
    short8 bf2v = *(const short8*)(pw + s * 2048 + 1024);
    short8 bf3  = *(const short8*)(pw + s * 2048 + 1536);
    if (s < 7) {
      if (s & 1) { XLOAD(xA0, xA1, xA2, xA3, s + 1) }
      else       { XLOAD(xB0, xB1, xB2, xB3, s + 1) }
    }
    const short8 xf00 = (s & 1) ? xB0 : xA0;
    const short8 xf01 = (s & 1) ? xB1 : xA1;
    const short8 xf10 = (s & 1) ? xB2 : xA2;
    const short8 xf11 = (s & 1) ? xB3 : xA3;

    union { int i[4]; short8 v; } af;
    {
      short8 wf0 = *(const short8*)(lw + (4 * s + 0) * 512);
      short8 wf1 = *(const short8*)(lw + (4 * s + 1) * 512);
      floatx4 acc = *(const floatx4*)(lbf + (2 * s) * 256);   // acc init = bias
      acc = __builtin_amdgcn_mfma_f32_16x16x32_bf16(wf0, xf00, acc, 0, 0, 0);
      acc = __builtin_amdgcn_mfma_f32_16x16x32_bf16(wf1, xf01, acc, 0, 0, 0);
      af.i[0] = cvtpk(gelu_f(acc[0]), gelu_f(acc[1]));
      af.i[1] = cvtpk(gelu_f(acc[2]), gelu_f(acc[3]));
    }
    {
      short8 wf0 = *(const short8*)(lw + (4 * s + 2) * 512);
      short8 wf1 = *(const short8*)(lw + (4 * s + 3) * 512);
      floatx4 acc = *(const floatx4*)(lbf + (2 * s + 1) * 256);
      acc = __builtin_amdgcn_mfma_f32_16x16x32_bf16(wf0, xf10, acc, 0, 0, 0);
      acc = __builtin_amdgcn_mfma_f32_16x16x32_bf16(wf1, xf11, acc, 0, 0, 0);
      af.i[2] = cvtpk(gelu_f(acc[0]), gelu_f(acc[1]));
      af.i[3] = cvtpk(gelu_f(acc[2]), gelu_f(acc[3]));
    }

    c0 = __builtin_amdgcn_mfma_f32_16x16x32_bf16(af.v, bf0,  c0, 0, 0, 0);
    c1 = __builtin_amdgcn_mfma_f32_16x16x32_bf16(af.v, bf1,  c1, 0, 0, 0);
    c2 = __builtin_amdgcn_mfma_f32_16x16x32_bf16(af.v, bf2v, c2, 0, 0, 0);
    c3 = __builtin_amdgcn_mfma_f32_16x16x32_bf16(af.v, bf3,  c3, 0, 0, 0);
  }
#undef XLOAD

  // ---- y store (NT): col = np*64 + ot*16 + l15, rows rt*16 + lhi*4 + r ----
  floatx4 cc[4] = {c0, c1, c2, c3};
  float* pyb = y + (size_t)(rt * 16 + lhi * 4) * 1024 + np * 64 + l15;
#pragma unroll
  for (int ot = 0; ot < 4; ++ot) {
    const float bb = b2[np * 64 + ot * 16 + l15];
#pragma unroll
    for (int r = 0; r < 4; ++r)
      __builtin_nontemporal_store(cc[ot][r] + bb, pyb + ot * 16 + (size_t)r * 1024);
  }
}

extern "C" void kernel_launch(void* const* d_in, const int* in_sizes, int n_in,
                              void* d_out, int out_size, void* d_ws, size_t ws_size,
                              hipStream_t stream) {
  const float* x  = (const float*)d_in[0];
  const float* w1 = (const float*)d_in[1];
  const float* b1 = (const float*)d_in[2];
  const float* w2 = (const float*)d_in[3];
  const float* b2 = (const float*)d_in[4];
  float* y = (float*)d_out;

  short* w1p  = (short*)d_ws;                  // 512 KB
  short* w2p  = w1p + 16 * 256 * 64;           // 512 KB
  float* b1pf = (float*)(w2p + 16 * 256 * 64); // 256 KB (f32 frags)
  short* xT   = (short*)(b1pf + 16 * 16 * 64 * 4);  // 16 MB

  pack_k<<<160, 512, 0, stream>>>(w1, w2, b1, w1p, w2p, b1pf);
  pack_x<<<512, 256, 0, stream>>>(x, xT);
  fused_k<<<1024, 512, 0, stream>>>(xT, w1p, w2p, b1pf, b2, y);
}